// Round 1
// baseline (1084.994 us; speedup 1.0000x reference)
//
#include <hip/hip_runtime.h>
#include <stdint.h>

#define NN 4096
#define DD 64
#define GCOL 16
#define ROUNDS 32

typedef unsigned long long u64;
typedef unsigned int u32;

__device__ __forceinline__ u64 pk(float d, u32 idx) {
  return (((u64)__float_as_uint(d)) << 32) | (u64)idx;
}

// On-the-fly distance, bit-identical accumulation order (k ascending, fmaf).
__device__ __forceinline__ float distfly(const float* __restrict__ x,
                                         const float* __restrict__ y,
                                         float xxi, float yyj, int i, int j) {
  const float* xi = x + (size_t)i * DD;
  const float* yj = y + (size_t)j * DD;
  float dot = 0.f;
#pragma unroll
  for (int k = 0; k < DD; ++k) dot = fmaf(xi[k], yj[k], dot);
  float sq = (xxi + yyj) - 2.0f * dot;  // *2 exact -> single rounding either way
  return sqrtf(fmaxf(sq, 0.f));
}

__global__ void k_init(const float* __restrict__ x, const float* __restrict__ y,
                       float* xx, float* yy, int* rm, int* cm, int* FR, int* Fcnt) {
  int i = blockIdx.x * blockDim.x + threadIdx.x;
  if (i < NN) {
    const float* xi = x + (size_t)i * DD;
    const float* yi = y + (size_t)i * DD;
    float sx = 0.f, sy = 0.f;
#pragma unroll
    for (int k = 0; k < DD; ++k) { sx = fmaf(xi[k], xi[k], sx); sy = fmaf(yi[k], yi[k], sy); }
    xx[i] = sx; yy[i] = sy;
    rm[i] = -1; cm[i] = -1; FR[i] = i;
    if (i == 0) *Fcnt = NN;
  }
}

// C[i][j] = sqrt(max(xx[i]+yy[j]-2*dot, 0)), 64x64 tiles.
__global__ void k_build(const float* __restrict__ x, const float* __restrict__ y,
                        const float* __restrict__ xx, const float* __restrict__ yy,
                        float* __restrict__ C) {
  __shared__ float xs[64][65];
  __shared__ float ys[64][65];
  int t = threadIdx.x;
  int bi = blockIdx.y * 64, bj = blockIdx.x * 64;
  for (int e = t; e < 64 * 64; e += 256) {
    int r = e >> 6, c = e & 63;
    xs[r][c] = x[(size_t)(bi + r) * DD + c];
    ys[r][c] = y[(size_t)(bj + r) * DD + c];
  }
  __syncthreads();
  int tx = t & 15, ty = t >> 4;
  float acc[4][4];
#pragma unroll
  for (int r = 0; r < 4; ++r)
#pragma unroll
    for (int c = 0; c < 4; ++c) acc[r][c] = 0.f;
#pragma unroll
  for (int k = 0; k < 64; ++k) {
    float a[4], b[4];
#pragma unroll
    for (int r = 0; r < 4; ++r) a[r] = xs[ty * 4 + r][k];
#pragma unroll
    for (int c = 0; c < 4; ++c) b[c] = ys[tx * 4 + c][k];
#pragma unroll
    for (int r = 0; r < 4; ++r)
#pragma unroll
      for (int c = 0; c < 4; ++c) acc[r][c] = fmaf(a[r], b[c], acc[r][c]);
  }
#pragma unroll
  for (int r = 0; r < 4; ++r) {
    int i = bi + ty * 4 + r;
    float xxi = xx[i];
    float4 v;
    float* vp = (float*)&v;
#pragma unroll
    for (int c = 0; c < 4; ++c) {
      int j = bj + tx * 4 + c;
      float sq = (xxi + yy[j]) - 2.0f * acc[r][c];
      vp[c] = sqrtf(fmaxf(sq, 0.f));
    }
    *(float4*)(C + (size_t)i * NN + bj + tx * 4) = v;
  }
}

template <bool USEC>
__global__ void k_rowpass(const float* __restrict__ C,
                          const float* __restrict__ x, const float* __restrict__ y,
                          const float* __restrict__ xx, const float* __restrict__ yy,
                          const int* __restrict__ cm, const int* __restrict__ FR,
                          const int* __restrict__ Fcnt, u64* __restrict__ rowbest) {
  int b = blockIdx.x;
  if (b >= *Fcnt) return;
  int i = FR[b];
  __shared__ float xsh[DD];
  __shared__ u64 red[256];
  int t = threadIdx.x;
  if (!USEC) { if (t < DD) xsh[t] = x[(size_t)i * DD + t]; }
  __syncthreads();
  float xxi = xx[i];
  u64 best = ~0ull;
  for (int j = t; j < NN; j += 256) {
    if (cm[j] != -1) continue;
    float d;
    if (USEC) {
      d = C[(size_t)i * NN + j];
    } else {
      const float* yj = y + (size_t)j * DD;
      float dot = 0.f;
#pragma unroll
      for (int k = 0; k < DD; ++k) dot = fmaf(xsh[k], yj[k], dot);
      float sq = (xxi + yy[j]) - 2.0f * dot;
      d = sqrtf(fmaxf(sq, 0.f));
    }
    u64 key = pk(d, (u32)j);
    if (key < best) best = key;
  }
  red[t] = best;
  __syncthreads();
  for (int s = 128; s > 0; s >>= 1) {
    if (t < s) { if (red[t + s] < red[t]) red[t] = red[t + s]; }
    __syncthreads();
  }
  if (t == 0) rowbest[i] = red[0];
}

template <bool USEC>
__global__ void k_colpass(const float* __restrict__ C,
                          const float* __restrict__ x, const float* __restrict__ y,
                          const float* __restrict__ xx, const float* __restrict__ yy,
                          const int* __restrict__ cm, const int* __restrict__ FR,
                          const int* __restrict__ Fcnt, u64* __restrict__ colpart) {
  int t = threadIdx.x;
  int j = blockIdx.x * 256 + t;
  int g = blockIdx.y;
  int F = *Fcnt;
  if (F == 0) return;
  int b0 = (g * F) / GCOL, b1 = ((g + 1) * F) / GCOL;
  u64 best = ~0ull;
  if (cm[j] == -1) {
    float yyj = yy[j];
    if (USEC) {
      for (int b = b0; b < b1; ++b) {
        int i = FR[b];
        u64 key = pk(C[(size_t)i * NN + j], (u32)i);
        if (key < best) best = key;
      }
    } else {
      float4 yr[16];
      const float4* yj4 = (const float4*)(y + (size_t)j * DD);
#pragma unroll
      for (int q = 0; q < 16; ++q) yr[q] = yj4[q];
      for (int b = b0; b < b1; ++b) {
        int i = FR[b];
        const float4* xi4 = (const float4*)(x + (size_t)i * DD);
        float dot = 0.f;
#pragma unroll
        for (int q = 0; q < 16; ++q) {
          float4 a = xi4[q], bb = yr[q];
          dot = fmaf(a.x, bb.x, dot); dot = fmaf(a.y, bb.y, dot);
          dot = fmaf(a.z, bb.z, dot); dot = fmaf(a.w, bb.w, dot);
        }
        float sq = (xx[i] + yyj) - 2.0f * dot;
        float d = sqrtf(fmaxf(sq, 0.f));
        u64 key = pk(d, (u32)i);
        if (key < best) best = key;
      }
    }
  }
  colpart[(size_t)g * NN + j] = best;
}

__global__ void k_accept(const u64* __restrict__ colpart, const u64* __restrict__ rowbest,
                         int* rm, int* cm, int* FR, int* Fcnt) {
  __shared__ int scnt;
  int t = threadIdx.x;
  if (*Fcnt == 0) return;  // already complete
  for (int j = t; j < NN; j += 1024) {
    if (cm[j] != -1) continue;
    u64 best = ~0ull;
#pragma unroll
    for (int g = 0; g < GCOL; ++g) {
      u64 v = colpart[(size_t)g * NN + j];
      if (v < best) best = v;
    }
    if (best == ~0ull) continue;
    int i = (int)(u32)best;
    if ((u32)(rowbest[i] & 0xffffffffu) == (u32)j) { rm[i] = j; cm[j] = i; }
  }
  __syncthreads();
  if (t == 0) scnt = 0;
  __syncthreads();
  for (int i = t; i < NN; i += 1024)
    if (rm[i] == -1) { int p = atomicAdd(&scnt, 1); FR[p] = i; }
  __syncthreads();
  if (t == 0) *Fcnt = scnt;
}

// Sequential greedy on whatever remains: guaranteed exact completion.
template <bool USEC>
__global__ void k_cleanup(const float* __restrict__ C,
                          const float* __restrict__ x, const float* __restrict__ y,
                          const float* __restrict__ xx, const float* __restrict__ yy,
                          int* rm, int* cm, int* FR) {
  __shared__ int scnt;
  __shared__ u64 red[1024];
  int t = threadIdx.x;
  for (;;) {
    if (t == 0) scnt = 0;
    __syncthreads();
    for (int i = t; i < NN; i += 1024)
      if (rm[i] == -1) { int p = atomicAdd(&scnt, 1); FR[p] = i; }
    __syncthreads();
    int F = scnt;
    if (F == 0) break;
    u64 best = ~0ull;
    int total = F * NN;
    for (int idx = t; idx < total; idx += 1024) {
      int b = idx >> 12;       // NN = 4096
      int j = idx & 4095;
      if (cm[j] != -1) continue;
      int i = FR[b];
      float d;
      if (USEC) d = C[(size_t)i * NN + j];
      else d = distfly(x, y, xx[i], yy[j], i, j);
      u64 key = pk(d, (u32)(i * NN + j));  // tie-break by flat index
      if (key < best) best = key;
    }
    red[t] = best;
    __syncthreads();
    for (int s = 512; s > 0; s >>= 1) {
      if (t < s) { if (red[t + s] < red[t]) red[t] = red[t + s]; }
      __syncthreads();
    }
    if (t == 0) {
      u32 lo = (u32)red[0];
      int i = lo >> 12, j = lo & 4095;
      rm[i] = j; cm[j] = i;
    }
    __syncthreads();
  }
}

extern "C" void kernel_launch(void* const* d_in, const int* in_sizes, int n_in,
                              void* d_out, int out_size, void* d_ws, size_t ws_size,
                              hipStream_t stream) {
  const float* x = (const float*)d_in[0];
  const float* y = (const float*)d_in[1];
  int* cm = (int*)d_out;

  char* w = (char*)d_ws;
  float* xx = (float*)(w + 0);
  float* yy = (float*)(w + 16384);
  int* rm = (int*)(w + 32768);
  int* FR = (int*)(w + 49152);
  int* Fcnt = (int*)(w + 65536);
  u64* rowbest = (u64*)(w + 65664);
  u64* colpart = (u64*)(w + 65664 + 32768);
  float* C = (float*)(w + 1048576);

  size_t need = 1048576 + (size_t)NN * NN * 4;
  bool usec = ws_size >= need;

  k_init<<<dim3(16), 256, 0, stream>>>(x, y, xx, yy, rm, cm, FR, Fcnt);
  if (usec) {
    k_build<<<dim3(64, 64), 256, 0, stream>>>(x, y, xx, yy, C);
    for (int r = 0; r < ROUNDS; ++r) {
      k_rowpass<true><<<dim3(NN), 256, 0, stream>>>(C, x, y, xx, yy, cm, FR, Fcnt, rowbest);
      k_colpass<true><<<dim3(16, GCOL), 256, 0, stream>>>(C, x, y, xx, yy, cm, FR, Fcnt, colpart);
      k_accept<<<dim3(1), 1024, 0, stream>>>(colpart, rowbest, rm, cm, FR, Fcnt);
    }
    k_cleanup<true><<<dim3(1), 1024, 0, stream>>>(C, x, y, xx, yy, rm, cm, FR);
  } else {
    for (int r = 0; r < ROUNDS; ++r) {
      k_rowpass<false><<<dim3(NN), 256, 0, stream>>>(nullptr, x, y, xx, yy, cm, FR, Fcnt, rowbest);
      k_colpass<false><<<dim3(16, GCOL), 256, 0, stream>>>(nullptr, x, y, xx, yy, cm, FR, Fcnt, colpart);
      k_accept<<<dim3(1), 1024, 0, stream>>>(colpart, rowbest, rm, cm, FR, Fcnt);
    }
    k_cleanup<false><<<dim3(1), 1024, 0, stream>>>(nullptr, x, y, xx, yy, rm, cm, FR);
  }
}

// Round 2
// 1029.961 us; speedup vs baseline: 1.0534x; 1.0534x over previous
//
#include <hip/hip_runtime.h>
#include <stdint.h>

#define NN 4096
#define DD 64
#define GCOL 16
#define RCH 8
#define ROUNDS_FAST 20
#define ROUNDS_FB 32

typedef unsigned long long u64;
typedef unsigned int u32;

__device__ __forceinline__ u64 pk(float d, u32 idx) {
  return (((u64)__float_as_uint(d)) << 32) | (u64)idx;
}

// On-the-fly distance, bit-identical accumulation order (k ascending, fmaf).
__device__ __forceinline__ float distfly(const float* __restrict__ x,
                                         const float* __restrict__ y,
                                         float xxi, float yyj, int i, int j) {
  const float* xi = x + (size_t)i * DD;
  const float* yj = y + (size_t)j * DD;
  float dot = 0.f;
#pragma unroll
  for (int k = 0; k < DD; ++k) dot = fmaf(xi[k], yj[k], dot);
  float sq = (xxi + yyj) - 2.0f * dot;
  return sqrtf(fmaxf(sq, 0.f));
}

__global__ void k_init(const float* __restrict__ x, const float* __restrict__ y,
                       float* xx, float* yy, int* rm, int* cm, int* FR, int* Fcnt) {
  int i = blockIdx.x * blockDim.x + threadIdx.x;
  if (i < NN) {
    const float* xi = x + (size_t)i * DD;
    const float* yi = y + (size_t)i * DD;
    float sx = 0.f, sy = 0.f;
#pragma unroll
    for (int k = 0; k < DD; ++k) { sx = fmaf(xi[k], xi[k], sx); sy = fmaf(yi[k], yi[k], sy); }
    xx[i] = sx; yy[i] = sy;
    rm[i] = -1; cm[i] = -1; FR[i] = i;
    if (i == 0) *Fcnt = NN;
  }
}

// C[i][j] = sqrt(max(xx[i]+yy[j]-2*dot, 0)), 64x64 tiles. (unchanged, proven)
__global__ void k_build(const float* __restrict__ x, const float* __restrict__ y,
                        const float* __restrict__ xx, const float* __restrict__ yy,
                        float* __restrict__ C) {
  __shared__ float xs[64][65];
  __shared__ float ys[64][65];
  int t = threadIdx.x;
  int bi = blockIdx.y * 64, bj = blockIdx.x * 64;
  for (int e = t; e < 64 * 64; e += 256) {
    int r = e >> 6, c = e & 63;
    xs[r][c] = x[(size_t)(bi + r) * DD + c];
    ys[r][c] = y[(size_t)(bj + r) * DD + c];
  }
  __syncthreads();
  int tx = t & 15, ty = t >> 4;
  float acc[4][4];
#pragma unroll
  for (int r = 0; r < 4; ++r)
#pragma unroll
    for (int c = 0; c < 4; ++c) acc[r][c] = 0.f;
#pragma unroll
  for (int k = 0; k < 64; ++k) {
    float a[4], b[4];
#pragma unroll
    for (int r = 0; r < 4; ++r) a[r] = xs[ty * 4 + r][k];
#pragma unroll
    for (int c = 0; c < 4; ++c) b[c] = ys[tx * 4 + c][k];
#pragma unroll
    for (int r = 0; r < 4; ++r)
#pragma unroll
      for (int c = 0; c < 4; ++c) acc[r][c] = fmaf(a[r], b[c], acc[r][c]);
  }
#pragma unroll
  for (int r = 0; r < 4; ++r) {
    int i = bi + ty * 4 + r;
    float xxi = xx[i];
    float4 v;
    float* vp = (float*)&v;
#pragma unroll
    for (int c = 0; c < 4; ++c) {
      int j = bj + tx * 4 + c;
      float sq = (xxi + yy[j]) - 2.0f * acc[r][c];
      vp[c] = sqrtf(fmaxf(sq, 0.f));
    }
    *(float4*)(C + (size_t)i * NN + bj + tx * 4) = v;
  }
}

// ---------- fast path (C materialized) ----------

// One block per row, gated on rm[i]; vectorized scan of free columns.
__global__ void k_rowpass2(const float* __restrict__ C, const int* __restrict__ rm,
                           const int* __restrict__ cm, u64* __restrict__ rowbest) {
  int i = blockIdx.x;
  if (rm[i] != -1) return;
  int t = threadIdx.x;
  __shared__ u64 red[256];
  const float* Ci = C + (size_t)i * NN;
  u64 best = ~0ull;
  for (int j0 = t * 4; j0 < NN; j0 += 1024) {
    float4 v = *(const float4*)(Ci + j0);
    int4 m = *(const int4*)(cm + j0);
    const float* vp = (const float*)&v;
    const int* mp = (const int*)&m;
#pragma unroll
    for (int c = 0; c < 4; ++c) {
      if (mp[c] == -1) {
        u64 key = pk(vp[c], (u32)(j0 + c));
        if (key < best) best = key;
      }
    }
  }
  red[t] = best;
  __syncthreads();
  for (int s = 128; s > 0; s >>= 1) {
    if (t < s) { if (red[t + s] < red[t]) red[t] = red[t + s]; }
    __syncthreads();
  }
  if (t == 0) rowbest[i] = red[0];
}

// 64 columns per block x RCH row-chunks; coalesced row reads, uniform rm gate.
__global__ void k_colpass2(const float* __restrict__ C, const int* __restrict__ rm,
                           const int* __restrict__ cm, u64* __restrict__ colpart) {
  int t = threadIdx.x;
  int lane = t & 63, rg = t >> 6;
  int j = blockIdx.x * 64 + lane;
  int i0 = blockIdx.y * (NN / RCH), i1 = i0 + NN / RCH;
  bool jfree = (cm[j] == -1);
  if (__ballot(jfree) == 0ull) return;  // uniform across all 4 waves
  __shared__ u64 red[4][64];
  u64 best = ~0ull;
  for (int i = i0 + rg; i < i1; i += 4) {
    if (rm[i] != -1) continue;  // uniform within wave
    if (jfree) {
      u64 key = pk(C[(size_t)i * NN + j], (u32)i);
      if (key < best) best = key;
    }
  }
  red[rg][lane] = best;
  __syncthreads();
  if (rg == 0) {
    u64 b = red[0][lane];
#pragma unroll
    for (int g = 1; g < 4; ++g) if (red[g][lane] < b) b = red[g][lane];
    colpart[(size_t)blockIdx.y * NN + j] = b;
  }
}

// 16 blocks x 256: combine partials, accept mutual minima, decrement Fcnt.
__global__ void k_accept2(const u64* __restrict__ colpart, const u64* __restrict__ rowbest,
                          int* rm, int* cm, int* Fcnt) {
  if (*Fcnt == 0) return;
  int j = blockIdx.x * 256 + threadIdx.x;
  if (cm[j] != -1) return;
  u64 best = ~0ull;
#pragma unroll
  for (int g = 0; g < RCH; ++g) {
    u64 v = colpart[(size_t)g * NN + j];
    if (v < best) best = v;
  }
  if (best == ~0ull) return;
  int i = (int)(u32)best;
  if ((u32)(rowbest[i] & 0xffffffffu) == (u32)j) {
    rm[i] = j; cm[j] = i;
    atomicSub(Fcnt, 1);
  }
}

// ---------- fallback path (no C in workspace) — unchanged, proven ----------

template <bool USEC>
__global__ void k_rowpass(const float* __restrict__ C,
                          const float* __restrict__ x, const float* __restrict__ y,
                          const float* __restrict__ xx, const float* __restrict__ yy,
                          const int* __restrict__ cm, const int* __restrict__ FR,
                          const int* __restrict__ Fcnt, u64* __restrict__ rowbest) {
  int b = blockIdx.x;
  if (b >= *Fcnt) return;
  int i = FR[b];
  __shared__ float xsh[DD];
  __shared__ u64 red[256];
  int t = threadIdx.x;
  if (!USEC) { if (t < DD) xsh[t] = x[(size_t)i * DD + t]; }
  __syncthreads();
  float xxi = xx[i];
  u64 best = ~0ull;
  for (int j = t; j < NN; j += 256) {
    if (cm[j] != -1) continue;
    float d;
    if (USEC) {
      d = C[(size_t)i * NN + j];
    } else {
      const float* yj = y + (size_t)j * DD;
      float dot = 0.f;
#pragma unroll
      for (int k = 0; k < DD; ++k) dot = fmaf(xsh[k], yj[k], dot);
      float sq = (xxi + yy[j]) - 2.0f * dot;
      d = sqrtf(fmaxf(sq, 0.f));
    }
    u64 key = pk(d, (u32)j);
    if (key < best) best = key;
  }
  red[t] = best;
  __syncthreads();
  for (int s = 128; s > 0; s >>= 1) {
    if (t < s) { if (red[t + s] < red[t]) red[t] = red[t + s]; }
    __syncthreads();
  }
  if (t == 0) rowbest[i] = red[0];
}

template <bool USEC>
__global__ void k_colpass(const float* __restrict__ C,
                          const float* __restrict__ x, const float* __restrict__ y,
                          const float* __restrict__ xx, const float* __restrict__ yy,
                          const int* __restrict__ cm, const int* __restrict__ FR,
                          const int* __restrict__ Fcnt, u64* __restrict__ colpart) {
  int t = threadIdx.x;
  int j = blockIdx.x * 256 + t;
  int g = blockIdx.y;
  int F = *Fcnt;
  if (F == 0) return;
  int b0 = (g * F) / GCOL, b1 = ((g + 1) * F) / GCOL;
  u64 best = ~0ull;
  if (cm[j] == -1) {
    float yyj = yy[j];
    if (USEC) {
      for (int b = b0; b < b1; ++b) {
        int i = FR[b];
        u64 key = pk(C[(size_t)i * NN + j], (u32)i);
        if (key < best) best = key;
      }
    } else {
      float4 yr[16];
      const float4* yj4 = (const float4*)(y + (size_t)j * DD);
#pragma unroll
      for (int q = 0; q < 16; ++q) yr[q] = yj4[q];
      for (int b = b0; b < b1; ++b) {
        int i = FR[b];
        const float4* xi4 = (const float4*)(x + (size_t)i * DD);
        float dot = 0.f;
#pragma unroll
        for (int q = 0; q < 16; ++q) {
          float4 a = xi4[q], bb = yr[q];
          dot = fmaf(a.x, bb.x, dot); dot = fmaf(a.y, bb.y, dot);
          dot = fmaf(a.z, bb.z, dot); dot = fmaf(a.w, bb.w, dot);
        }
        float sq = (xx[i] + yyj) - 2.0f * dot;
        float d = sqrtf(fmaxf(sq, 0.f));
        u64 key = pk(d, (u32)i);
        if (key < best) best = key;
      }
    }
  }
  colpart[(size_t)g * NN + j] = best;
}

__global__ void k_accept(const u64* __restrict__ colpart, const u64* __restrict__ rowbest,
                         int* rm, int* cm, int* FR, int* Fcnt) {
  __shared__ int scnt;
  int t = threadIdx.x;
  if (*Fcnt == 0) return;
  for (int j = t; j < NN; j += 1024) {
    if (cm[j] != -1) continue;
    u64 best = ~0ull;
#pragma unroll
    for (int g = 0; g < GCOL; ++g) {
      u64 v = colpart[(size_t)g * NN + j];
      if (v < best) best = v;
    }
    if (best == ~0ull) continue;
    int i = (int)(u32)best;
    if ((u32)(rowbest[i] & 0xffffffffu) == (u32)j) { rm[i] = j; cm[j] = i; }
  }
  __syncthreads();
  if (t == 0) scnt = 0;
  __syncthreads();
  for (int i = t; i < NN; i += 1024)
    if (rm[i] == -1) { int p = atomicAdd(&scnt, 1); FR[p] = i; }
  __syncthreads();
  if (t == 0) *Fcnt = scnt;
}

// Sequential greedy on whatever remains: guaranteed exact completion.
template <bool USEC>
__global__ void k_cleanup(const float* __restrict__ C,
                          const float* __restrict__ x, const float* __restrict__ y,
                          const float* __restrict__ xx, const float* __restrict__ yy,
                          int* rm, int* cm, int* FR) {
  __shared__ int scnt;
  __shared__ u64 red[1024];
  int t = threadIdx.x;
  for (;;) {
    if (t == 0) scnt = 0;
    __syncthreads();
    for (int i = t; i < NN; i += 1024)
      if (rm[i] == -1) { int p = atomicAdd(&scnt, 1); FR[p] = i; }
    __syncthreads();
    int F = scnt;
    if (F == 0) break;
    u64 best = ~0ull;
    int total = F * NN;
    for (int idx = t; idx < total; idx += 1024) {
      int b = idx >> 12;
      int j = idx & 4095;
      if (cm[j] != -1) continue;
      int i = FR[b];
      float d;
      if (USEC) d = C[(size_t)i * NN + j];
      else d = distfly(x, y, xx[i], yy[j], i, j);
      u64 key = pk(d, (u32)(i * NN + j));
      if (key < best) best = key;
    }
    red[t] = best;
    __syncthreads();
    for (int s = 512; s > 0; s >>= 1) {
      if (t < s) { if (red[t + s] < red[t]) red[t] = red[t + s]; }
      __syncthreads();
    }
    if (t == 0) {
      u32 lo = (u32)red[0];
      int i = lo >> 12, j = lo & 4095;
      rm[i] = j; cm[j] = i;
    }
    __syncthreads();
  }
}

extern "C" void kernel_launch(void* const* d_in, const int* in_sizes, int n_in,
                              void* d_out, int out_size, void* d_ws, size_t ws_size,
                              hipStream_t stream) {
  const float* x = (const float*)d_in[0];
  const float* y = (const float*)d_in[1];
  int* cm = (int*)d_out;

  char* w = (char*)d_ws;
  float* xx = (float*)(w + 0);
  float* yy = (float*)(w + 16384);
  int* rm = (int*)(w + 32768);
  int* FR = (int*)(w + 49152);
  int* Fcnt = (int*)(w + 65536);
  u64* rowbest = (u64*)(w + 65664);
  u64* colpart = (u64*)(w + 65664 + 32768);
  float* C = (float*)(w + 1048576);

  size_t need = 1048576 + (size_t)NN * NN * 4;
  bool usec = ws_size >= need;

  k_init<<<dim3(16), 256, 0, stream>>>(x, y, xx, yy, rm, cm, FR, Fcnt);
  if (usec) {
    k_build<<<dim3(64, 64), 256, 0, stream>>>(x, y, xx, yy, C);
    for (int r = 0; r < ROUNDS_FAST; ++r) {
      k_rowpass2<<<dim3(NN), 256, 0, stream>>>(C, rm, cm, rowbest);
      k_colpass2<<<dim3(64, RCH), 256, 0, stream>>>(C, rm, cm, colpart);
      k_accept2<<<dim3(16), 256, 0, stream>>>(colpart, rowbest, rm, cm, Fcnt);
    }
    k_cleanup<true><<<dim3(1), 1024, 0, stream>>>(C, x, y, xx, yy, rm, cm, FR);
  } else {
    for (int r = 0; r < ROUNDS_FB; ++r) {
      k_rowpass<false><<<dim3(NN), 256, 0, stream>>>(nullptr, x, y, xx, yy, cm, FR, Fcnt, rowbest);
      k_colpass<false><<<dim3(16, GCOL), 256, 0, stream>>>(nullptr, x, y, xx, yy, cm, FR, Fcnt, colpart);
      k_accept<<<dim3(1), 1024, 0, stream>>>(colpart, rowbest, rm, cm, FR, Fcnt);
    }
    k_cleanup<false><<<dim3(1), 1024, 0, stream>>>(nullptr, x, y, xx, yy, rm, cm, FR);
  }
}